// Round 21
// baseline (910.336 us; speedup 1.0000x reference)
//
#include <hip/hip_runtime.h>

#define SEQ 2048
#define DIM 1024
#define NH 16
#define HDIM 64
#define PFF 4096
#define NROWS 4096  // B*S
#define BATCH 2
#define NQKV 3072

typedef unsigned short u16;
typedef unsigned int u32;
typedef __attribute__((ext_vector_type(8))) short short8;
typedef __attribute__((ext_vector_type(4))) float f32x4;
typedef __attribute__((ext_vector_type(16))) float f32x16;

__device__ inline float b2f(u16 u){ return __uint_as_float(((u32)u)<<16); }
__device__ inline u16 f2b(float f){
  u32 u = __float_as_uint(f);
  u32 r = u + 0x7FFFu + ((u>>16)&1u);
  return (u16)(r>>16);
}
__device__ __forceinline__ float fexp2(float x){      // v_exp_f32 = 2^x
  float r; asm("v_exp_f32 %0, %1" : "=v"(r) : "v"(x)); return r;
}

// C-style casts: clang allows addrspacecast via C-style cast (static_cast does not)
#define AS1C(p) ((const __attribute__((address_space(1))) unsigned int*)(p))
#define AS3P(p) ((__attribute__((address_space(3))) unsigned int*)(p))

// ================= merged prep: cast src, transpose 4x DIM^2 W, W1T, W2T, pack3 =================
__global__ __launch_bounds__(256) void k_prep(
    const float* __restrict__ src, u16* __restrict__ Xbf,
    const float* __restrict__ Wq, const float* __restrict__ Wk,
    const float* __restrict__ Wv, const float* __restrict__ Wo,
    u16* __restrict__ WqkvT, u16* __restrict__ WoT,
    const float* __restrict__ W1, u16* __restrict__ W1T,
    const float* __restrict__ W2, u16* __restrict__ W2T,
    const float* __restrict__ bq, const float* __restrict__ bk,
    const float* __restrict__ bv, float* __restrict__ bqkv){
  __shared__ float tile[32][33];
  const int lid = blockIdx.x, tid = threadIdx.x;
  if (lid < 4096){
    int i = lid*256 + tid;
    float4 v = ((const float4*)src)[i];
    ushort4 o;
    o.x = f2b(v.x); o.y = f2b(v.y); o.z = f2b(v.z); o.w = f2b(v.w);
    ((ushort4*)Xbf)[i] = o;
    return;
  }
  int tx = tid & 31, ty = tid >> 5;
  if (lid < 8192){
    int rem = lid - 4096;
    int z = rem >> 10; rem &= 1023;
    const float* in = z==0 ? Wq : (z==1 ? Wk : (z==2 ? Wv : Wo));
    u16* out = (z<3) ? (WqkvT + (size_t)z*DIM*DIM) : WoT;
    int c0 = (rem & 31)*32, r0 = (rem >> 5)*32;
    #pragma unroll
    for (int i=0;i<4;++i)
      tile[ty+i*8][tx] = in[(size_t)(r0+ty+i*8)*DIM + c0 + tx];
    __syncthreads();
    #pragma unroll
    for (int i=0;i<4;++i)
      out[(size_t)(c0+ty+i*8)*DIM + r0 + tx] = f2b(tile[tx][ty+i*8]);
    return;
  }
  if (lid < 12288){
    int rem = lid - 8192;                 // W1 [DIM][PFF] -> W1T [PFF][DIM]
    int c0 = (rem & 127)*32, r0 = (rem >> 7)*32;
    #pragma unroll
    for (int i=0;i<4;++i)
      tile[ty+i*8][tx] = W1[(size_t)(r0+ty+i*8)*PFF + c0 + tx];
    __syncthreads();
    #pragma unroll
    for (int i=0;i<4;++i)
      W1T[(size_t)(c0+ty+i*8)*DIM + r0 + tx] = f2b(tile[tx][ty+i*8]);
    return;
  }
  if (lid < 16384){
    int rem = lid - 12288;                // W2 [PFF][DIM] -> W2T [DIM][PFF]
    int c0 = (rem & 31)*32, r0 = (rem >> 5)*32;
    #pragma unroll
    for (int i=0;i<4;++i)
      tile[ty+i*8][tx] = W2[(size_t)(r0+ty+i*8)*DIM + c0 + tx];
    __syncthreads();
    #pragma unroll
    for (int i=0;i<4;++i)
      W2T[(size_t)(c0+ty+i*8)*PFF + r0 + tx] = f2b(tile[tx][ty+i*8]);
    return;
  }
  {
    int i = (lid - 16384)*256 + tid;
    if (i < NQKV)
      bqkv[i] = i < 1024 ? bq[i] : (i < 2048 ? bk[i-1024] : bv[i-2048]);
  }
}

// ================= 256x256 GEMM, BK=32, 2-phase, 64KB dbuf LDS -> 2 blocks/CU =================
// r21: halve BK so double-buffered LDS fits 64KB and TWO blocks co-reside per CU.
// When one block's waves sit at a barrier, the other block's waves issue MFMA/loads
// (m114 cross-block overlap) - recovers the lockstep stall of the 1-block/CU variant.
// Same subtile layout ([16 rows][32 k] per 1KB; linear gload_lds dest; ro frag read),
// same hazard chain per K-tile: ds_read(buf) -> stage(buf^1) -> barrier -> MFMA -> barrier,
// vmcnt(0) before tile-end barrier. SPLIT>1: split-K over gridDim.z, bf16 partials.
template<bool RELU, bool BF16OUT, int SPLIT>
__global__ __launch_bounds__(512, 4) void k_gemm256(
    const u16* __restrict__ A, const u16* __restrict__ Bt,
    const float* __restrict__ bias, void* __restrict__ Cp,
    int M, int N, int Kc, int lda, int ldb){
  extern __shared__ char lds[];          // 2 bufs x (A 16KB + B 16KB) = 64KB
  const int tid = threadIdx.x;
  const int lane = tid & 63, wid = tid >> 6;
  const int quad = lane >> 4, l15 = lane & 15;
  const int wm = wid >> 2, wn = wid & 3;
  const int ro = (l15*4 + quad)*16;      // in-subtile frag byte offset
  const int srow = lane >> 2;            // staging: row within [16][32] subtile
  const int sk   = (lane & 3)*8;         // staging: k elems within subtile
  const int nwg = gridDim.x * gridDim.y;
  int lid = blockIdx.y * gridDim.x + blockIdx.x;
  lid = (lid & 7) * (nwg >> 3) + (lid >> 3);
  const int bx = lid % gridDim.x, by = lid / gridDim.x;
  const int rowBase = by*256, colBase = bx*256;
  const u16* Az = A  + (size_t)blockIdx.z * Kc;
  const u16* Bz = Bt + (size_t)blockIdx.z * Kc;

  f32x4 acc[8][4] = {};

  // stage half i (i=0,1): each wave loads A-subtile idx and B-subtile idx (1KB each)
  auto stage2 = [&](int buf, int k0, int i){
    int idx = i*8 + wid;                 // 0..15
    const u16* ga = Az + (size_t)(rowBase + idx*16 + srow)*lda + k0 + sk;
    __builtin_amdgcn_global_load_lds(AS1C(ga), AS3P(lds + buf*32768 + idx*1024), 16, 0, 0);
    const u16* gb = Bz + (size_t)(colBase + idx*16 + srow)*ldb + k0 + sk;
    __builtin_amdgcn_global_load_lds(AS1C(gb), AS3P(lds + buf*32768 + 16384 + idx*1024), 16, 0, 0);
  };

  stage2(0, 0, 0);
  stage2(0, 0, 1);
  __syncthreads();

  const int NT = Kc >> 5;                // K-tiles of 32
  #pragma unroll 1
  for (int t=0; t<NT; ++t){
    const int buf = t & 1;
    const bool pf = (t+1 < NT);
    const int k0n = (t+1)*32;
    char* Ab = lds + buf*32768;
    char* Bb = Ab + 16384;
    short8 a0[4], a1[4], bb[4];

    // ---- phase 1: read A m-half0 + all B; stage half 0 of next; MFMA m0
    #pragma unroll
    for (int mf=0; mf<4; ++mf)
      a0[mf] = *(const short8*)(Ab + (wm*8+mf)*1024 + ro);
    #pragma unroll
    for (int nf=0; nf<4; ++nf)
      bb[nf] = *(const short8*)(Bb + (wn*4+nf)*1024 + ro);
    if (pf) stage2(buf^1, k0n, 0);
    __builtin_amdgcn_s_barrier();
    __builtin_amdgcn_s_setprio(1);
    #pragma unroll
    for (int mf=0; mf<4; ++mf)
      #pragma unroll
      for (int nf=0; nf<4; ++nf)
        acc[mf][nf] = __builtin_amdgcn_mfma_f32_16x16x32_bf16(a0[mf], bb[nf], acc[mf][nf], 0,0,0);
    __builtin_amdgcn_s_setprio(0);
    __builtin_amdgcn_s_barrier();

    // ---- phase 2: read A m-half1; stage half 1 of next; MFMA m1; drain; tile-end barrier
    #pragma unroll
    for (int mf=0; mf<4; ++mf)
      a1[mf] = *(const short8*)(Ab + (wm*8+4+mf)*1024 + ro);
    if (pf) stage2(buf^1, k0n, 1);
    __builtin_amdgcn_s_barrier();
    __builtin_amdgcn_s_setprio(1);
    #pragma unroll
    for (int mf=0; mf<4; ++mf)
      #pragma unroll
      for (int nf=0; nf<4; ++nf)
        acc[4+mf][nf] = __builtin_amdgcn_mfma_f32_16x16x32_bf16(a1[mf], bb[nf], acc[4+mf][nf], 0,0,0);
    __builtin_amdgcn_s_setprio(0);
    if (pf) asm volatile("s_waitcnt vmcnt(0)" ::: "memory");
    __builtin_amdgcn_s_barrier();
  }

  u16* Cb = (u16*)Cp + (SPLIT > 1 ? (size_t)blockIdx.z * M * N : 0);
  float* Cf = (float*)Cp + (SPLIT > 1 ? (size_t)blockIdx.z * M * N : 0);
  #pragma unroll
  for (int mf=0; mf<8; ++mf){
    #pragma unroll
    for (int nf=0; nf<4; ++nf){
      int col = colBase + wn*64 + nf*16 + l15;
      float bv = (SPLIT == 1 || blockIdx.z == 0) ? bias[col] : 0.f;
      #pragma unroll
      for (int j=0; j<4; ++j){
        int row = rowBase + wm*128 + mf*16 + quad*4 + j;
        float v = acc[mf][nf][j] + bv;
        if (RELU) v = fmaxf(v, 0.f);
        if (BF16OUT) Cb[(size_t)row*N + col] = f2b(v);
        else         Cf[(size_t)row*N + col] = v;
      }
    }
  }
}

// ------------- merged RoPE (Q,K cols) + V transpose: disjoint column ranges -------------
__global__ __launch_bounds__(256) void k_rope_tv(
    u16* __restrict__ QKV, u16* __restrict__ VT,
    const float* __restrict__ cosT, const float* __restrict__ sinT){
  __shared__ u16 tile[32][34];
  const int lid = blockIdx.x, tid = threadIdx.x;
  if (lid < 8192){
    int idx = lid*256 + tid;
    int row = idx >> 9, p = idx & 511;
    int s = row & (SEQ-1);
    float c = cosT[s*512 + p], sn = sinT[s*512 + p];
    u16* qp = QKV + (size_t)row*NQKV + 2*p;
    u16* kp = qp + 1024;
    ushort2 q = *(ushort2*)qp;
    ushort2 k = *(ushort2*)kp;
    float qx = b2f(q.x), qy = b2f(q.y), kx = b2f(k.x), ky = b2f(k.y);
    const float scale = 0.125f * 1.44269504f;   // 1/sqrt(HD) * log2(e)
    ushort2 qo, ko;
    qo.x = f2b((qx*c - qy*sn)*scale);
    qo.y = f2b((qx*sn + qy*c)*scale);
    ko.x = f2b(kx*c - ky*sn);
    ko.y = f2b(kx*sn + ky*c);
    *(ushort2*)qp = qo;
    *(ushort2*)kp = ko;
    return;
  }
  int rem = lid - 8192;
  int tx = tid & 31, ty = tid >> 5;
  int d0 = (rem & 31)*32, r0 = (rem >> 5)*32;
  #pragma unroll
  for (int i=0;i<4;++i)
    tile[ty+i*8][tx] = QKV[(size_t)(r0+ty+i*8)*NQKV + 2048 + d0 + tx];
  __syncthreads();
  #pragma unroll
  for (int i=0;i<4;++i)
    VT[(size_t)(d0+ty+i*8)*NROWS + r0 + tx] = tile[tx][ty+i*8];
}

// ---------- flash attention v10: Q-tile 256 (8 waves), NO-MAX exp2 softmax, XCD-grouped ----------
// Linear grid p in [0,256): p = c + 8*qt + 64*d; all 8 qt-blocks of one (h,b) share p%8
// -> same XCD, K/V panel fetched into one L2 (T1 mechanism).
__global__ __launch_bounds__(512) void k_attn(
    const u16* __restrict__ QKV, const u16* __restrict__ VT, u16* __restrict__ Xo){
  const int p = blockIdx.x;
  const int qt = (p >> 3) & 7;
  const int g  = (p & 7) + 8*(p >> 6);
  const int h  = g & 15, b = g >> 4;
  const int tid = threadIdx.x, lane = tid & 63, wid = tid >> 6;
  const int l31 = lane & 31, hi = lane >> 5;
  __shared__ __align__(16) char lds[32768];
  const int srow = lane >> 3, scol = lane & 7;

  short8 qf[4];
  {
    const u16* qrow = QKV + (size_t)(b*SEQ + qt*256 + wid*32 + l31)*NQKV + h*HDIM;
    #pragma unroll
    for (int dk=0; dk<4; ++dk)
      qf[dk] = *(const short8*)(qrow + dk*16 + 8*hi);
  }
  float s_run = 0.f;
  f32x16 oacc[2] = {};
  const size_t krow0 = (size_t)(b*SEQ);

  auto do_stage = [&](int buf, int kt){
    char* kdst = lds + buf*16384;
    char* vdst = kdst + 8192;
    int row = wid*8 + srow;
    int c = scol ^ (row & 7);
    const u16* gk = QKV + (krow0 + kt*64 + row)*NQKV + 1024 + h*HDIM + c*8;
    __builtin_amdgcn_global_load_lds(AS1C(gk), AS3P(kdst + wid*1024), 16, 0, 0);
    const u16* gv = VT + (size_t)(h*HDIM + row)*NROWS + b*SEQ + kt*64 + c*8;
    __builtin_amdgcn_global_load_lds(AS1C(gv), AS3P(vdst + wid*1024), 16, 0, 0);
  };

  auto do_tile = [&](int buf){
    char* kb = lds + buf*16384;
    char* vb = kb + 8192;
    f32x16 pacc[2] = {};
    __builtin_amdgcn_s_setprio(1);
    #pragma unroll
    for (int kbk=0;kbk<2;++kbk){
      #pragma unroll
      for (int dk=0;dk<4;++dk){
        int row = kbk*32 + l31;
        short8 kf = *(const short8*)(kb + ((row*128 + dk*32 + 16*hi) ^ ((row&7)<<4)));
        pacc[kbk] = __builtin_amdgcn_mfma_f32_32x32x16_bf16(kf, qf[dk], pacc[kbk], 0,0,0);
      }
    }
    __builtin_amdgcn_s_setprio(0);
    // ---- P = 2^S (no max-shift; |S_log2| bounded ~6 at this model scale), fused sum+pack
    float psum = 0.f;
    short8 pa[4];
    #pragma unroll
    for (int kbk=0;kbk<2;++kbk){
      #pragma unroll
      for (int s=0;s<2;++s){
        float e0 = fexp2(pacc[kbk][8*s+0]);
        float e1 = fexp2(pacc[kbk][8*s+1]);
        float e2 = fexp2(pacc[kbk][8*s+2]);
        float e3 = fexp2(pacc[kbk][8*s+3]);
        float e4 = fexp2(pacc[kbk][8*s+4]);
        float e5 = fexp2(pacc[kbk][8*s+5]);
        float e6 = fexp2(pacc[kbk][8*s+6]);
        float e7 = fexp2(pacc[kbk][8*s+7]);
        psum += (e0+e1)+(e2+e3)+((e4+e5)+(e6+e7));
        u32 X0, X1, Y0, Y1;
        asm("v_cvt_pk_bf16_f32 %0, %1, %2" : "=v"(X0) : "v"(e0), "v"(e1));
        asm("v_cvt_pk_bf16_f32 %0, %1, %2" : "=v"(X1) : "v"(e2), "v"(e3));
        asm("v_cvt_pk_bf16_f32 %0, %1, %2" : "=v"(Y0) : "v"(e4), "v"(e5));
        asm("v_cvt_pk_bf16_f32 %0, %1, %2" : "=v"(Y1) : "v"(e6), "v"(e7));
        asm volatile("v_permlane32_swap_b32 %0, %1" : "+v"(X0), "+v"(Y0));
        asm volatile("v_permlane32_swap_b32 %0, %1" : "+v"(X1), "+v"(Y1));
        union { u32 w[4]; short8 s8; } pu;
        pu.w[0] = X0; pu.w[1] = X1; pu.w[2] = Y0; pu.w[3] = Y1;
        pa[2*kbk+s] = pu.s8;
      }
    }
    s_run += psum;            // cross-half reduce deferred to epilogue
    __builtin_amdgcn_s_setprio(1);
    #pragma unroll
    for (int db=0;db<2;++db){
      #pragma unroll
      for (int ks=0;ks<4;++ks){
        int row = db*32 + l31;
        short8 vf = *(const short8*)(vb + ((row*128 + ks*32 + 16*hi) ^ ((row&7)<<4)));
        oacc[db] = __builtin_amdgcn_mfma_f32_32x32x16_bf16(pa[ks], vf, oacc[db], 0,0,0);
      }
    }
    __builtin_amdgcn_s_setprio(0);
  };

  do_stage(0, 0);
  __syncthreads();
  const int NT = SEQ/64;
  #pragma unroll 1
  for (int kt=0; kt<NT; kt+=2){
    do_stage(1, kt+1);
    do_tile(0);
    __syncthreads();
    if (kt+2 < NT) do_stage(0, kt+2);
    do_tile(1);
    __syncthreads();
  }
  s_run += __shfl_xor(s_run, 32);   // deferred cross-half reduce
  #pragma unroll
  for (int r=0;r<16;++r){
    int crow = (r&3) + 8*(r>>2) + 4*hi;
    float sq = __shfl(s_run, crow);
    float rs = __builtin_amdgcn_rcpf(sq);
    int grow = b*SEQ + qt*256 + wid*32 + crow;
    Xo[(size_t)grow*DIM + h*HDIM + l31]      = f2b(oacc[0][r] * rs);
    Xo[(size_t)grow*DIM + h*HDIM + 32 + l31] = f2b(oacc[1][r] * rs);
  }
}

// -------- residual (fp32 or bf16) + PARTS bf16 partials + layernorm; fp32/bf16 outs --------
template<int PARTS, bool WF32, bool WBF, bool RESBF>
__global__ __launch_bounds__(256) void k_lnp(
    const void* __restrict__ a, const u16* __restrict__ p,
    const float* __restrict__ g, const float* __restrict__ be,
    float* __restrict__ outf, u16* __restrict__ outb){
  const int row = blockIdx.x, tid = threadIdx.x;
  __shared__ float red[8];
  float x0, x1, x2, x3;
  if (RESBF){
    ushort4 av = ((const ushort4*)((const u16*)a + (size_t)row*DIM))[tid];
    x0 = b2f(av.x); x1 = b2f(av.y); x2 = b2f(av.z); x3 = b2f(av.w);
  } else {
    float4 av = ((const float4*)((const float*)a + (size_t)row*DIM))[tid];
    x0 = av.x; x1 = av.y; x2 = av.z; x3 = av.w;
  }
  #pragma unroll
  for (int z=0; z<PARTS; ++z){
    ushort4 pv = ((const ushort4*)(p + (size_t)z*NROWS*DIM + (size_t)row*DIM))[tid];
    x0 += b2f(pv.x); x1 += b2f(pv.y); x2 += b2f(pv.z); x3 += b2f(pv.w);
  }
  float s = x0+x1+x2+x3;
  #pragma unroll
  for (int o=32;o>=1;o>>=1) s += __shfl_down(s, o);
  if ((tid&63)==0) red[tid>>6] = s;
  __syncthreads();
  float mean = (red[0]+red[1]+red[2]+red[3]) * (1.0f/DIM);
  float d0=x0-mean, d1=x1-mean, d2=x2-mean, d3=x3-mean;
  float vs = d0*d0+d1*d1+d2*d2+d3*d3;
  #pragma unroll
  for (int o=32;o>=1;o>>=1) vs += __shfl_down(vs, o);
  if ((tid&63)==0) red[4+(tid>>6)] = vs;
  __syncthreads();
  float var = (red[4]+red[5]+red[6]+red[7]) * (1.0f/DIM);
  float rs = rsqrtf(var + 1e-5f);
  float4 gv = ((const float4*)g)[tid];
  float4 bev = ((const float4*)be)[tid];
  float4 y;
  y.x = d0*rs*gv.x + bev.x;
  y.y = d1*rs*gv.y + bev.y;
  y.z = d2*rs*gv.z + bev.z;
  y.w = d3*rs*gv.w + bev.w;
  if (WF32)
    ((float4*)(outf + (size_t)row*DIM))[tid] = y;
  if (WBF){
    ushort4 o4; o4.x=f2b(y.x); o4.y=f2b(y.y); o4.z=f2b(y.z); o4.w=f2b(y.w);
    ((ushort4*)(outb + (size_t)row*DIM))[tid] = o4;
  }
}

extern "C" void kernel_launch(void* const* d_in, const int* in_sizes, int n_in,
                              void* d_out, int out_size, void* d_ws, size_t ws_size,
                              hipStream_t stream){
  (void)in_sizes; (void)n_in; (void)out_size; (void)ws_size;
  const float* src  = (const float*)d_in[0];
  const float* Wq   = (const float*)d_in[1];
  const float* bq   = (const float*)d_in[2];
  const float* Wk   = (const float*)d_in[3];
  const float* bk   = (const float*)d_in[4];
  const float* Wv   = (const float*)d_in[5];
  const float* bv   = (const float*)d_in[6];
  const float* Wo   = (const float*)d_in[7];
  const float* bo   = (const float*)d_in[8];
  const float* ln1g = (const float*)d_in[9];
  const float* ln1b = (const float*)d_in[10];
  const float* W1   = (const float*)d_in[11];
  const float* b1   = (const float*)d_in[12];
  const float* W2   = (const float*)d_in[13];
  const float* b2   = (const float*)d_in[14];
  const float* ln2g = (const float*)d_in[15];
  const float* ln2b = (const float*)d_in[16];
  const float* rc   = (const float*)d_in[17];
  const float* rsn  = (const float*)d_in[18];

  char* ws = (char*)d_ws;
  const size_t MB = (size_t)1<<20;
  u16* Xbf   = (u16*)(ws);
  u16* QKV   = (u16*)(ws + 8*MB);
  u16* VTb   = (u16*)(ws + 32*MB);
  u16* aob   = (u16*)(ws + 8*MB);       // Wo bf16 partials: z at +z*8MB (4x)
  u16* ff2b  = (u16*)(ws + 8*MB);       // FF2 bf16 partials: z at +z*8MB (4x)
  u16* xat   = (u16*)(ws + 40*MB);
  u16* hbf   = (u16*)(ws + 48*MB);
  u16* WqkvT = (u16*)(ws + 56*MB);
  u16* WoT   = (u16*)(ws + 62*MB);
  u16* W1T   = (u16*)(ws + 64*MB);
  u16* W2T   = (u16*)(ws + 72*MB);
  u16* ff1   = (u16*)(ws + 80*MB);
  float* bqkv= (float*)(ws + 128*MB);

  hipFuncSetAttribute((const void*)&k_gemm256<false,true,1>,
                      hipFuncAttributeMaxDynamicSharedMemorySize, 65536);
  hipFuncSetAttribute((const void*)&k_gemm256<true,true,1>,
                      hipFuncAttributeMaxDynamicSharedMemorySize, 65536);
  hipFuncSetAttribute((const void*)&k_gemm256<false,true,4>,
                      hipFuncAttributeMaxDynamicSharedMemorySize, 65536);

  dim3 blk(256);
  // merged prep: src cast + 6 weight transposes + bias pack
  k_prep<<<dim3(16396), blk, 0, stream>>>(src, Xbf, Wq, Wk, Wv, Wo, WqkvT, WoT,
                                          W1, W1T, W2, W2T, bq, bk, bv, bqkv);
  // fused QKV GEMM (BK=32 2-phase 256^2, 2 blocks/CU)
  k_gemm256<false,true,1><<<dim3(NQKV/256, NROWS/256), dim3(512), 65536, stream>>>(
      Xbf, WqkvT, bqkv, QKV, NROWS, NQKV, DIM, DIM, DIM);
  // merged rope + V transpose
  k_rope_tv<<<dim3(12288), blk, 0, stream>>>(QKV, VTb, rc, rsn);
  // attention: 256-row q-tile, 8 waves, XCD-grouped linear grid (256 blocks = 1/CU)
  k_attn<<<dim3(256), dim3(512), 0, stream>>>(QKV, VTb, xat);
  // Wo GEMM, concurrent split-K=4, bf16 partials (256 blocks)
  k_gemm256<false,true,4><<<dim3(DIM/256, NROWS/256, 4), dim3(512), 65536, stream>>>(
      xat, WoT, bo, aob, NROWS, DIM, 256, DIM, DIM);
  // ln1: residual fp32 src + 4 partials -> hbf only
  k_lnp<4,false,true,false><<<dim3(NROWS), blk, 0, stream>>>(
      src, aob, ln1g, ln1b, nullptr, hbf);
  // FF1 GEMM (BK=32 2-phase 256^2) + ReLU
  k_gemm256<true,true,1><<<dim3(PFF/256, NROWS/256), dim3(512), 65536, stream>>>(
      hbf, W1T, b1, ff1, NROWS, PFF, DIM, DIM, DIM);
  // FF2 GEMM, concurrent split-K=4, bf16 partials (256 blocks)
  k_gemm256<false,true,4><<<dim3(DIM/256, NROWS/256, 4), dim3(512), 65536, stream>>>(
      ff1, W2T, b2, ff2b, NROWS, DIM, 1024, PFF, PFF);
  // ln2: residual bf16 hbf + 4 partials -> d_out fp32
  k_lnp<4,true,false,true><<<dim3(NROWS), blk, 0, stream>>>(
      hbf, ff2b, ln2g, ln2b, (float*)d_out, nullptr);
}

// Round 22
// 228.644 us; speedup vs baseline: 3.9815x; 3.9815x over previous
//
#include <hip/hip_runtime.h>

#define SEQ 2048
#define DIM 1024
#define NH 16
#define HDIM 64
#define PFF 4096
#define NROWS 4096  // B*S
#define BATCH 2
#define NQKV 3072

typedef unsigned short u16;
typedef unsigned int u32;
typedef __attribute__((ext_vector_type(8))) short short8;
typedef __attribute__((ext_vector_type(4))) float f32x4;
typedef __attribute__((ext_vector_type(16))) float f32x16;

__device__ inline float b2f(u16 u){ return __uint_as_float(((u32)u)<<16); }
__device__ inline u16 f2b(float f){
  u32 u = __float_as_uint(f);
  u32 r = u + 0x7FFFu + ((u>>16)&1u);
  return (u16)(r>>16);
}
__device__ __forceinline__ float fexp2(float x){      // v_exp_f32 = 2^x
  float r; asm("v_exp_f32 %0, %1" : "=v"(r) : "v"(x)); return r;
}

// C-style casts: clang allows addrspacecast via C-style cast (static_cast does not)
#define AS1C(p) ((const __attribute__((address_space(1))) unsigned int*)(p))
#define AS3P(p) ((__attribute__((address_space(3))) unsigned int*)(p))

// ================= merged prep: cast src, transpose 4x DIM^2 W, W1T, W2T, pack3 =================
__global__ __launch_bounds__(256) void k_prep(
    const float* __restrict__ src, u16* __restrict__ Xbf,
    const float* __restrict__ Wq, const float* __restrict__ Wk,
    const float* __restrict__ Wv, const float* __restrict__ Wo,
    u16* __restrict__ WqkvT, u16* __restrict__ WoT,
    const float* __restrict__ W1, u16* __restrict__ W1T,
    const float* __restrict__ W2, u16* __restrict__ W2T,
    const float* __restrict__ bq, const float* __restrict__ bk,
    const float* __restrict__ bv, float* __restrict__ bqkv){
  __shared__ float tile[32][33];
  const int lid = blockIdx.x, tid = threadIdx.x;
  if (lid < 4096){
    int i = lid*256 + tid;
    float4 v = ((const float4*)src)[i];
    ushort4 o;
    o.x = f2b(v.x); o.y = f2b(v.y); o.z = f2b(v.z); o.w = f2b(v.w);
    ((ushort4*)Xbf)[i] = o;
    return;
  }
  int tx = tid & 31, ty = tid >> 5;
  if (lid < 8192){
    int rem = lid - 4096;
    int z = rem >> 10; rem &= 1023;
    const float* in = z==0 ? Wq : (z==1 ? Wk : (z==2 ? Wv : Wo));
    u16* out = (z<3) ? (WqkvT + (size_t)z*DIM*DIM) : WoT;
    int c0 = (rem & 31)*32, r0 = (rem >> 5)*32;
    #pragma unroll
    for (int i=0;i<4;++i)
      tile[ty+i*8][tx] = in[(size_t)(r0+ty+i*8)*DIM + c0 + tx];
    __syncthreads();
    #pragma unroll
    for (int i=0;i<4;++i)
      out[(size_t)(c0+ty+i*8)*DIM + r0 + tx] = f2b(tile[tx][ty+i*8]);
    return;
  }
  if (lid < 12288){
    int rem = lid - 8192;                 // W1 [DIM][PFF] -> W1T [PFF][DIM]
    int c0 = (rem & 127)*32, r0 = (rem >> 7)*32;
    #pragma unroll
    for (int i=0;i<4;++i)
      tile[ty+i*8][tx] = W1[(size_t)(r0+ty+i*8)*PFF + c0 + tx];
    __syncthreads();
    #pragma unroll
    for (int i=0;i<4;++i)
      W1T[(size_t)(c0+ty+i*8)*DIM + r0 + tx] = f2b(tile[tx][ty+i*8]);
    return;
  }
  if (lid < 16384){
    int rem = lid - 12288;                // W2 [PFF][DIM] -> W2T [DIM][PFF]
    int c0 = (rem & 31)*32, r0 = (rem >> 5)*32;
    #pragma unroll
    for (int i=0;i<4;++i)
      tile[ty+i*8][tx] = W2[(size_t)(r0+ty+i*8)*DIM + c0 + tx];
    __syncthreads();
    #pragma unroll
    for (int i=0;i<4;++i)
      W2T[(size_t)(c0+ty+i*8)*PFF + r0 + tx] = f2b(tile[tx][ty+i*8]);
    return;
  }
  {
    int i = (lid - 16384)*256 + tid;
    if (i < NQKV)
      bqkv[i] = i < 1024 ? bq[i] : (i < 2048 ? bk[i-1024] : bv[i-2048]);
  }
}

// ================= 8-phase 256x256 GEMM (T2+T3+T4+T5 stack, m201-style) =================
template<bool RELU, bool BF16OUT, int SPLIT>
__global__ __launch_bounds__(512, 2) void k_gemm256(
    const u16* __restrict__ A, const u16* __restrict__ Bt,
    const float* __restrict__ bias, void* __restrict__ Cp,
    int M, int N, int Kc, int lda, int ldb){
  extern __shared__ char lds[];
  const int tid = threadIdx.x;
  const int lane = tid & 63, wid = tid >> 6;
  const int quad = lane >> 4, l15 = lane & 15;
  const int wm = wid >> 2, wn = wid & 3;
  const int ro = (l15*4 + quad)*16;
  const int srow = lane >> 2;
  const int sk   = (lane & 3)*8;
  const int nwg = gridDim.x * gridDim.y;
  int lid = blockIdx.y * gridDim.x + blockIdx.x;
  lid = (lid & 7) * (nwg >> 3) + (lid >> 3);
  const int bx = lid % gridDim.x, by = lid / gridDim.x;
  const int rowBase = by*256, colBase = bx*256;
  const u16* Az = A  + (size_t)blockIdx.z * Kc;
  const u16* Bz = Bt + (size_t)blockIdx.z * Kc;

  f32x4 acc[8][4] = {};

  auto stage2 = [&](int buf, int k0, int i){
    int idx = i*8 + wid;
    int rs = idx >> 1, ks = idx & 1;
    const u16* ga = Az + (size_t)(rowBase + rs*16 + srow)*lda + k0 + ks*32 + sk;
    __builtin_amdgcn_global_load_lds(AS1C(ga), AS3P(lds + buf*65536 + idx*1024), 16, 0, 0);
    const u16* gb = Bz + (size_t)(colBase + rs*16 + srow)*ldb + k0 + ks*32 + sk;
    __builtin_amdgcn_global_load_lds(AS1C(gb), AS3P(lds + buf*65536 + 32768 + idx*1024), 16, 0, 0);
  };

  #pragma unroll
  for (int i=0;i<4;++i) stage2(0, 0, i);
  __syncthreads();

  const int NT = Kc >> 6;
  #pragma unroll 1
  for (int t=0; t<NT; ++t){
    const int buf = t & 1;
    const bool pf = (t+1 < NT);
    const int k0n = (t+1)*64;
    char* Ab = lds + buf*65536;
    char* Bb = Ab + 32768;
    short8 a0[4][2], a1[4][2], b0[2][2], b1[2][2];

    // ---- phase 1
    #pragma unroll
    for (int mf=0; mf<4; ++mf)
      #pragma unroll
      for (int kk=0; kk<2; ++kk)
        a0[mf][kk] = *(const short8*)(Ab + ((wm*8+mf)*2+kk)*1024 + ro);
    #pragma unroll
    for (int nf=0; nf<2; ++nf)
      #pragma unroll
      for (int kk=0; kk<2; ++kk)
        b0[nf][kk] = *(const short8*)(Bb + ((wn*4+nf)*2+kk)*1024 + ro);
    if (pf){ stage2(buf^1, k0n, 0); stage2(buf^1, k0n, 1); }
    __builtin_amdgcn_s_barrier();
    __builtin_amdgcn_s_setprio(1);
    #pragma unroll
    for (int mf=0; mf<4; ++mf)
      #pragma unroll
      for (int nf=0; nf<2; ++nf)
        #pragma unroll
        for (int kk=0; kk<2; ++kk)
          acc[mf][nf] = __builtin_amdgcn_mfma_f32_16x16x32_bf16(a0[mf][kk], b0[nf][kk], acc[mf][nf], 0,0,0);
    __builtin_amdgcn_s_setprio(0);
    __builtin_amdgcn_s_barrier();

    // ---- phase 2
    #pragma unroll
    for (int nf=0; nf<2; ++nf)
      #pragma unroll
      for (int kk=0; kk<2; ++kk)
        b1[nf][kk] = *(const short8*)(Bb + ((wn*4+2+nf)*2+kk)*1024 + ro);
    if (pf){ stage2(buf^1, k0n, 2); stage2(buf^1, k0n, 3); }
    __builtin_amdgcn_s_barrier();
    __builtin_amdgcn_s_setprio(1);
    #pragma unroll
    for (int mf=0; mf<4; ++mf)
      #pragma unroll
      for (int nf=0; nf<2; ++nf)
        #pragma unroll
        for (int kk=0; kk<2; ++kk)
          acc[mf][2+nf] = __builtin_amdgcn_mfma_f32_16x16x32_bf16(a0[mf][kk], b1[nf][kk], acc[mf][2+nf], 0,0,0);
    __builtin_amdgcn_s_setprio(0);
    __builtin_amdgcn_s_barrier();

    // ---- phase 3
    #pragma unroll
    for (int mf=0; mf<4; ++mf)
      #pragma unroll
      for (int kk=0; kk<2; ++kk)
        a1[mf][kk] = *(const short8*)(Ab + ((wm*8+4+mf)*2+kk)*1024 + ro);
    __builtin_amdgcn_s_barrier();
    __builtin_amdgcn_s_setprio(1);
    #pragma unroll
    for (int mf=0; mf<4; ++mf)
      #pragma unroll
      for (int nf=0; nf<2; ++nf)
        #pragma unroll
        for (int kk=0; kk<2; ++kk)
          acc[4+mf][2+nf] = __builtin_amdgcn_mfma_f32_16x16x32_bf16(a1[mf][kk], b1[nf][kk], acc[4+mf][2+nf], 0,0,0);
    __builtin_amdgcn_s_setprio(0);
    __builtin_amdgcn_s_barrier();

    // ---- phase 4
    if (pf) asm volatile("s_waitcnt vmcnt(0)" ::: "memory");
    __builtin_amdgcn_s_barrier();
    __builtin_amdgcn_s_setprio(1);
    #pragma unroll
    for (int mf=0; mf<4; ++mf)
      #pragma unroll
      for (int nf=0; nf<2; ++nf)
        #pragma unroll
        for (int kk=0; kk<2; ++kk)
          acc[4+mf][nf] = __builtin_amdgcn_mfma_f32_16x16x32_bf16(a1[mf][kk], b0[nf][kk], acc[4+mf][nf], 0,0,0);
    __builtin_amdgcn_s_setprio(0);
    __builtin_amdgcn_s_barrier();
  }

  u16* Cb = (u16*)Cp + (SPLIT > 1 ? (size_t)blockIdx.z * M * N : 0);
  float* Cf = (float*)Cp + (SPLIT > 1 ? (size_t)blockIdx.z * M * N : 0);
  #pragma unroll
  for (int mf=0; mf<8; ++mf){
    #pragma unroll
    for (int nf=0; nf<4; ++nf){
      int col = colBase + wn*64 + nf*16 + l15;
      float bv = (SPLIT == 1 || blockIdx.z == 0) ? bias[col] : 0.f;
      #pragma unroll
      for (int j=0; j<4; ++j){
        int row = rowBase + wm*128 + mf*16 + quad*4 + j;
        float v = acc[mf][nf][j] + bv;
        if (RELU) v = fmaxf(v, 0.f);
        if (BF16OUT) Cb[(size_t)row*N + col] = f2b(v);
        else         Cf[(size_t)row*N + col] = v;
      }
    }
  }
}

// ------------- merged RoPE (Q,K cols) + V transpose: disjoint column ranges -------------
__global__ __launch_bounds__(256) void k_rope_tv(
    u16* __restrict__ QKV, u16* __restrict__ VT,
    const float* __restrict__ cosT, const float* __restrict__ sinT){
  __shared__ u16 tile[32][34];
  const int lid = blockIdx.x, tid = threadIdx.x;
  if (lid < 8192){
    int idx = lid*256 + tid;
    int row = idx >> 9, p = idx & 511;
    int s = row & (SEQ-1);
    float c = cosT[s*512 + p], sn = sinT[s*512 + p];
    u16* qp = QKV + (size_t)row*NQKV + 2*p;
    u16* kp = qp + 1024;
    ushort2 q = *(ushort2*)qp;
    ushort2 k = *(ushort2*)kp;
    float qx = b2f(q.x), qy = b2f(q.y), kx = b2f(k.x), ky = b2f(k.y);
    const float scale = 0.125f * 1.44269504f;   // 1/sqrt(HD) * log2(e)
    ushort2 qo, ko;
    qo.x = f2b((qx*c - qy*sn)*scale);
    qo.y = f2b((qx*sn + qy*c)*scale);
    ko.x = f2b(kx*c - ky*sn);
    ko.y = f2b(kx*sn + ky*c);
    *(ushort2*)qp = qo;
    *(ushort2*)kp = ko;
    return;
  }
  int rem = lid - 8192;
  int tx = tid & 31, ty = tid >> 5;
  int d0 = (rem & 31)*32, r0 = (rem >> 5)*32;
  #pragma unroll
  for (int i=0;i<4;++i)
    tile[ty+i*8][tx] = QKV[(size_t)(r0+ty+i*8)*NQKV + 2048 + d0 + tx];
  __syncthreads();
  #pragma unroll
  for (int i=0;i<4;++i)
    VT[(size_t)(d0+ty+i*8)*NROWS + r0 + tx] = tile[tx][ty+i*8];
}

// ---------- flash attention v10: Q-tile 256 (8 waves), NO-MAX exp2 softmax, XCD-grouped ----------
// Linear grid p in [0,256): p = c + 8*qt + 64*d; all 8 qt-blocks of one (h,b) share p%8
// -> same XCD, K/V panel fetched into one L2 (T1 mechanism).
__global__ __launch_bounds__(512) void k_attn(
    const u16* __restrict__ QKV, const u16* __restrict__ VT, u16* __restrict__ Xo){
  const int p = blockIdx.x;
  const int qt = (p >> 3) & 7;
  const int g  = (p & 7) + 8*(p >> 6);
  const int h  = g & 15, b = g >> 4;
  const int tid = threadIdx.x, lane = tid & 63, wid = tid >> 6;
  const int l31 = lane & 31, hi = lane >> 5;
  __shared__ __align__(16) char lds[32768];
  const int srow = lane >> 3, scol = lane & 7;

  short8 qf[4];
  {
    const u16* qrow = QKV + (size_t)(b*SEQ + qt*256 + wid*32 + l31)*NQKV + h*HDIM;
    #pragma unroll
    for (int dk=0; dk<4; ++dk)
      qf[dk] = *(const short8*)(qrow + dk*16 + 8*hi);
  }
  float s_run = 0.f;
  f32x16 oacc[2] = {};
  const size_t krow0 = (size_t)(b*SEQ);

  auto do_stage = [&](int buf, int kt){
    char* kdst = lds + buf*16384;
    char* vdst = kdst + 8192;
    int row = wid*8 + srow;
    int c = scol ^ (row & 7);
    const u16* gk = QKV + (krow0 + kt*64 + row)*NQKV + 1024 + h*HDIM + c*8;
    __builtin_amdgcn_global_load_lds(AS1C(gk), AS3P(kdst + wid*1024), 16, 0, 0);
    const u16* gv = VT + (size_t)(h*HDIM + row)*NROWS + b*SEQ + kt*64 + c*8;
    __builtin_amdgcn_global_load_lds(AS1C(gv), AS3P(vdst + wid*1024), 16, 0, 0);
  };

  auto do_tile = [&](int buf){
    char* kb = lds + buf*16384;
    char* vb = kb + 8192;
    f32x16 pacc[2] = {};
    __builtin_amdgcn_s_setprio(1);
    #pragma unroll
    for (int kbk=0;kbk<2;++kbk){
      #pragma unroll
      for (int dk=0;dk<4;++dk){
        int row = kbk*32 + l31;
        short8 kf = *(const short8*)(kb + ((row*128 + dk*32 + 16*hi) ^ ((row&7)<<4)));
        pacc[kbk] = __builtin_amdgcn_mfma_f32_32x32x16_bf16(kf, qf[dk], pacc[kbk], 0,0,0);
      }
    }
    __builtin_amdgcn_s_setprio(0);
    // ---- P = 2^S (no max-shift; |S_log2| bounded ~6 at this model scale), fused sum+pack
    float psum = 0.f;
    short8 pa[4];
    #pragma unroll
    for (int kbk=0;kbk<2;++kbk){
      #pragma unroll
      for (int s=0;s<2;++s){
        float e0 = fexp2(pacc[kbk][8*s+0]);
        float e1 = fexp2(pacc[kbk][8*s+1]);
        float e2 = fexp2(pacc[kbk][8*s+2]);
        float e3 = fexp2(pacc[kbk][8*s+3]);
        float e4 = fexp2(pacc[kbk][8*s+4]);
        float e5 = fexp2(pacc[kbk][8*s+5]);
        float e6 = fexp2(pacc[kbk][8*s+6]);
        float e7 = fexp2(pacc[kbk][8*s+7]);
        psum += (e0+e1)+(e2+e3)+((e4+e5)+(e6+e7));
        u32 X0, X1, Y0, Y1;
        asm("v_cvt_pk_bf16_f32 %0, %1, %2" : "=v"(X0) : "v"(e0), "v"(e1));
        asm("v_cvt_pk_bf16_f32 %0, %1, %2" : "=v"(X1) : "v"(e2), "v"(e3));
        asm("v_cvt_pk_bf16_f32 %0, %1, %2" : "=v"(Y0) : "v"(e4), "v"(e5));
        asm("v_cvt_pk_bf16_f32 %0, %1, %2" : "=v"(Y1) : "v"(e6), "v"(e7));
        asm volatile("v_permlane32_swap_b32 %0, %1" : "+v"(X0), "+v"(Y0));
        asm volatile("v_permlane32_swap_b32 %0, %1" : "+v"(X1), "+v"(Y1));
        union { u32 w[4]; short8 s8; } pu;
        pu.w[0] = X0; pu.w[1] = X1; pu.w[2] = Y0; pu.w[3] = Y1;
        pa[2*kbk+s] = pu.s8;
      }
    }
    s_run += psum;            // cross-half reduce deferred to epilogue
    __builtin_amdgcn_s_setprio(1);
    #pragma unroll
    for (int db=0;db<2;++db){
      #pragma unroll
      for (int ks=0;ks<4;++ks){
        int row = db*32 + l31;
        short8 vf = *(const short8*)(vb + ((row*128 + ks*32 + 16*hi) ^ ((row&7)<<4)));
        oacc[db] = __builtin_amdgcn_mfma_f32_32x32x16_bf16(pa[ks], vf, oacc[db], 0,0,0);
      }
    }
    __builtin_amdgcn_s_setprio(0);
  };

  do_stage(0, 0);
  __syncthreads();
  const int NT = SEQ/64;
  #pragma unroll 1
  for (int kt=0; kt<NT; kt+=2){
    do_stage(1, kt+1);
    do_tile(0);
    __syncthreads();
    if (kt+2 < NT) do_stage(0, kt+2);
    do_tile(1);
    __syncthreads();
  }
  s_run += __shfl_xor(s_run, 32);   // deferred cross-half reduce
  #pragma unroll
  for (int r=0;r<16;++r){
    int crow = (r&3) + 8*(r>>2) + 4*hi;
    float sq = __shfl(s_run, crow);
    float rs = __builtin_amdgcn_rcpf(sq);
    int grow = b*SEQ + qt*256 + wid*32 + crow;
    Xo[(size_t)grow*DIM + h*HDIM + l31]      = f2b(oacc[0][r] * rs);
    Xo[(size_t)grow*DIM + h*HDIM + 32 + l31] = f2b(oacc[1][r] * rs);
  }
}

// -------- residual (fp32 or bf16) + PARTS bf16 partials + layernorm; fp32/bf16 outs --------
template<int PARTS, bool WF32, bool WBF, bool RESBF>
__global__ __launch_bounds__(256) void k_lnp(
    const void* __restrict__ a, const u16* __restrict__ p,
    const float* __restrict__ g, const float* __restrict__ be,
    float* __restrict__ outf, u16* __restrict__ outb){
  const int row = blockIdx.x, tid = threadIdx.x;
  __shared__ float red[8];
  float x0, x1, x2, x3;
  if (RESBF){
    ushort4 av = ((const ushort4*)((const u16*)a + (size_t)row*DIM))[tid];
    x0 = b2f(av.x); x1 = b2f(av.y); x2 = b2f(av.z); x3 = b2f(av.w);
  } else {
    float4 av = ((const float4*)((const float*)a + (size_t)row*DIM))[tid];
    x0 = av.x; x1 = av.y; x2 = av.z; x3 = av.w;
  }
  #pragma unroll
  for (int z=0; z<PARTS; ++z){
    ushort4 pv = ((const ushort4*)(p + (size_t)z*NROWS*DIM + (size_t)row*DIM))[tid];
    x0 += b2f(pv.x); x1 += b2f(pv.y); x2 += b2f(pv.z); x3 += b2f(pv.w);
  }
  float s = x0+x1+x2+x3;
  #pragma unroll
  for (int o=32;o>=1;o>>=1) s += __shfl_down(s, o);
  if ((tid&63)==0) red[tid>>6] = s;
  __syncthreads();
  float mean = (red[0]+red[1]+red[2]+red[3]) * (1.0f/DIM);
  float d0=x0-mean, d1=x1-mean, d2=x2-mean, d3=x3-mean;
  float vs = d0*d0+d1*d1+d2*d2+d3*d3;
  #pragma unroll
  for (int o=32;o>=1;o>>=1) vs += __shfl_down(vs, o);
  if ((tid&63)==0) red[4+(tid>>6)] = vs;
  __syncthreads();
  float var = (red[4]+red[5]+red[6]+red[7]) * (1.0f/DIM);
  float rs = rsqrtf(var + 1e-5f);
  float4 gv = ((const float4*)g)[tid];
  float4 bev = ((const float4*)be)[tid];
  float4 y;
  y.x = d0*rs*gv.x + bev.x;
  y.y = d1*rs*gv.y + bev.y;
  y.z = d2*rs*gv.z + bev.z;
  y.w = d3*rs*gv.w + bev.w;
  if (WF32)
    ((float4*)(outf + (size_t)row*DIM))[tid] = y;
  if (WBF){
    ushort4 o4; o4.x=f2b(y.x); o4.y=f2b(y.y); o4.z=f2b(y.z); o4.w=f2b(y.w);
    ((ushort4*)(outb + (size_t)row*DIM))[tid] = o4;
  }
}

extern "C" void kernel_launch(void* const* d_in, const int* in_sizes, int n_in,
                              void* d_out, int out_size, void* d_ws, size_t ws_size,
                              hipStream_t stream){
  (void)in_sizes; (void)n_in; (void)out_size; (void)ws_size;
  const float* src  = (const float*)d_in[0];
  const float* Wq   = (const float*)d_in[1];
  const float* bq   = (const float*)d_in[2];
  const float* Wk   = (const float*)d_in[3];
  const float* bk   = (const float*)d_in[4];
  const float* Wv   = (const float*)d_in[5];
  const float* bv   = (const float*)d_in[6];
  const float* Wo   = (const float*)d_in[7];
  const float* bo   = (const float*)d_in[8];
  const float* ln1g = (const float*)d_in[9];
  const float* ln1b = (const float*)d_in[10];
  const float* W1   = (const float*)d_in[11];
  const float* b1   = (const float*)d_in[12];
  const float* W2   = (const float*)d_in[13];
  const float* b2   = (const float*)d_in[14];
  const float* ln2g = (const float*)d_in[15];
  const float* ln2b = (const float*)d_in[16];
  const float* rc   = (const float*)d_in[17];
  const float* rsn  = (const float*)d_in[18];

  char* ws = (char*)d_ws;
  const size_t MB = (size_t)1<<20;
  u16* Xbf   = (u16*)(ws);
  u16* QKV   = (u16*)(ws + 8*MB);
  u16* VTb   = (u16*)(ws + 32*MB);
  u16* aob   = (u16*)(ws + 8*MB);       // Wo bf16 partials: z at +z*8MB (4x)
  u16* ff2b  = (u16*)(ws + 8*MB);       // FF2 bf16 partials: z at +z*8MB (4x)
  u16* xat   = (u16*)(ws + 40*MB);
  u16* hbf   = (u16*)(ws + 48*MB);
  u16* WqkvT = (u16*)(ws + 56*MB);
  u16* WoT   = (u16*)(ws + 62*MB);
  u16* W1T   = (u16*)(ws + 64*MB);
  u16* W2T   = (u16*)(ws + 72*MB);
  u16* ff1   = (u16*)(ws + 80*MB);
  float* bqkv= (float*)(ws + 128*MB);

  hipFuncSetAttribute((const void*)&k_gemm256<false,true,1>,
                      hipFuncAttributeMaxDynamicSharedMemorySize, 131072);
  hipFuncSetAttribute((const void*)&k_gemm256<true,true,1>,
                      hipFuncAttributeMaxDynamicSharedMemorySize, 131072);
  hipFuncSetAttribute((const void*)&k_gemm256<false,true,4>,
                      hipFuncAttributeMaxDynamicSharedMemorySize, 131072);

  dim3 blk(256);
  // merged prep: src cast + 6 weight transposes + bias pack
  k_prep<<<dim3(16396), blk, 0, stream>>>(src, Xbf, Wq, Wk, Wv, Wo, WqkvT, WoT,
                                          W1, W1T, W2, W2T, bq, bk, bv, bqkv);
  // fused QKV GEMM (8-phase 256^2)
  k_gemm256<false,true,1><<<dim3(NQKV/256, NROWS/256), dim3(512), 131072, stream>>>(
      Xbf, WqkvT, bqkv, QKV, NROWS, NQKV, DIM, DIM, DIM);
  // merged rope + V transpose
  k_rope_tv<<<dim3(12288), blk, 0, stream>>>(QKV, VTb, rc, rsn);
  // attention: 256-row q-tile, 8 waves, XCD-grouped linear grid (256 blocks = 1/CU)
  k_attn<<<dim3(256), dim3(512), 0, stream>>>(QKV, VTb, xat);
  // Wo GEMM (8-phase 256^2), concurrent split-K=4, bf16 partials (256 blocks = 1/CU)
  k_gemm256<false,true,4><<<dim3(DIM/256, NROWS/256, 4), dim3(512), 131072, stream>>>(
      xat, WoT, bo, aob, NROWS, DIM, 256, DIM, DIM);
  // ln1: residual fp32 src + 4 partials -> hbf only
  k_lnp<4,false,true,false><<<dim3(NROWS), blk, 0, stream>>>(
      src, aob, ln1g, ln1b, nullptr, hbf);
  // FF1 GEMM (8-phase 256^2) + ReLU
  k_gemm256<true,true,1><<<dim3(PFF/256, NROWS/256), dim3(512), 131072, stream>>>(
      hbf, W1T, b1, ff1, NROWS, PFF, DIM, DIM, DIM);
  // FF2 GEMM (8-phase 256^2), concurrent split-K=4, bf16 partials (256 blocks)
  k_gemm256<false,true,4><<<dim3(DIM/256, NROWS/256, 4), dim3(512), 131072, stream>>>(
      ff1, W2T, b2, ff2b, NROWS, DIM, 1024, PFF, PFF);
  // ln2: residual bf16 hbf + 4 partials -> d_out fp32
  k_lnp<4,true,false,true><<<dim3(NROWS), blk, 0, stream>>>(
      hbf, ff2b, ln2g, ln2b, (float*)d_out, nullptr);
}